// Round 13
// baseline (235.858 us; speedup 1.0000x reference)
//
#include <hip/hip_runtime.h>
#include <math.h>

typedef __attribute__((ext_vector_type(8))) short short8;
typedef __attribute__((ext_vector_type(4))) short short4v;
typedef __attribute__((ext_vector_type(4))) float f32x4;
typedef unsigned short ushort_t;
typedef unsigned int uint_t;

#define DIM 64
#define NE 1024
#define NROW 65536
#define NELEM (NROW * DIM)  // 4194304
#define MARGIN 0.02f
#define NBLK 2048

// ws layout (bytes):
#define OFF_BPACK 0      // 256 KB: bf16-split embed, MFMA B-frag order
#define OFF_CN 262144    // 4 KB: ||e_j||^2 fp32
#define OFF_ET 266240    // 256 KB: embed^T fp32 [code][d]
#define OFF_ACC 528384   // 1 KB: 8 f64 loss slots, stride 128 B
#define OFF_DONE 529408  // 4 B: completion counter

__device__ __forceinline__ ushort_t f2bf(float f) {
  uint_t u = __float_as_uint(f);
  uint_t r = (u + 0x7FFFu + ((u >> 16) & 1u)) >> 16;
  return (ushort_t)r;
}

// ---------------- prepack: embed -> {B-frag bf16 hi/lo, colnorms, embed^T}; zero acc/done
__global__ void prepack_kernel(const float* __restrict__ embed, ushort_t* __restrict__ bp,
                               float* __restrict__ cn, float* __restrict__ et,
                               double* __restrict__ acc, int* __restrict__ done) {
  const int lane = threadIdx.x;  // 64 threads
  const int blk = blockIdx.x;    // 256 blocks
  if (blk == 0) {
    if (lane < 8) acc[lane * 16] = 0.0;
    if (lane == 8) done[0] = 0;
  }
  const int code = blk * 4 + (lane >> 4);
  const int dg = lane & 15;  // 4 dims each
  const int d0 = dg * 4;
  float e[4];
  float nrm = 0.f;
#pragma unroll
  for (int q = 0; q < 4; ++q) {
    e[q] = embed[(d0 + q) * NE + code];
    nrm = fmaf(e[q], e[q], nrm);
  }
  float4 ev = {e[0], e[1], e[2], e[3]};
  *reinterpret_cast<float4*>(&et[(size_t)code * 64 + d0]) = ev;

  short4v hv, lv;
#pragma unroll
  for (int q = 0; q < 4; ++q) {
    ushort_t h = f2bf(e[q]);
    float hf = __uint_as_float((uint_t)h << 16);
    hv[q] = (short)h;
    lv[q] = (short)f2bf(e[q] - hf);
  }
  const int c16 = code >> 4, cl = code & 15;
  const int lane16 = cl + ((d0 >> 3) & 3) * 16;
  const int kk = d0 >> 5;
  const int j0 = d0 & 7;  // 0 or 4
  *reinterpret_cast<short4v*>(&bp[((size_t)(c16 * 4 + kk) * 64 + lane16) * 8 + j0]) = hv;
  *reinterpret_cast<short4v*>(&bp[((size_t)(c16 * 4 + 2 + kk) * 64 + lane16) * 8 + j0]) = lv;

#pragma unroll
  for (int off = 1; off <= 8; off <<= 1) nrm += __shfl_xor(nrm, off);
  if (dg == 0) cn[code] = nrm;
}

// ---------------- score: 1 wave / 32 rows; 3-product split-bf16 MFMA; in-block exact fixup;
// fused gather + loss; done-counter finalize. No barriers beyond the 1-wave block.
__launch_bounds__(64, 2)
__global__ void score_kernel(const float* __restrict__ input, const ushort_t* __restrict__ bp,
                             const float* __restrict__ cn, const float* __restrict__ et,
                             float* __restrict__ out, double* __restrict__ acc,
                             int* __restrict__ done) {
  __shared__ __align__(16) float cns[NE];  // colnorms; later reused as x-row scratch
  const int lane = threadIdx.x;
  const int col = lane & 15, g = lane >> 4;
  const long rowbase = (long)blockIdx.x * 32;

#pragma unroll
  for (int i = 0; i < 4; ++i) {
    int o = i * 256 + lane * 4;
    *reinterpret_cast<float4*>(&cns[o]) = *reinterpret_cast<const float4*>(&cn[o]);
  }

  short8 ah[2][2], al[2][2];
#pragma unroll
  for (int rt = 0; rt < 2; ++rt)
#pragma unroll
    for (int kk = 0; kk < 2; ++kk) {
      const float* xp = &input[(size_t)(rowbase + rt * 16 + col) * 64 + kk * 32 + g * 8];
      float4 x0 = *reinterpret_cast<const float4*>(xp);
      float4 x1 = *reinterpret_cast<const float4*>(xp + 4);
      float xs[8] = {x0.x, x0.y, x0.z, x0.w, x1.x, x1.y, x1.z, x1.w};
#pragma unroll
      for (int j = 0; j < 8; ++j) {
        ushort_t h = f2bf(xs[j]);
        ah[rt][kk][j] = (short)h;
        float hf = __uint_as_float((uint_t)h << 16);
        al[rt][kk][j] = (short)f2bf(xs[j] - hf);
      }
    }

  float v1[2][4], v2[2][4];
  int i1[2][4];
#pragma unroll
  for (int rt = 0; rt < 2; ++rt)
#pragma unroll
    for (int r = 0; r < 4; ++r) {
      v1[rt][r] = -INFINITY;
      v2[rt][r] = -INFINITY;
      i1[rt][r] = 0;
    }

  __syncthreads();  // 1-wave block: orders cns LDS writes before reads

  const short8* bpv = reinterpret_cast<const short8*>(bp);
  short8 b0h0, b0h1, b0l0, b0l1, b1h0, b1h1, b1l0, b1l1, b2h0, b2h1, b2l0, b2l1;

#define LOADB(B, cc)                       \
  {                                        \
    b##B##h0 = bpv[(cc)*256 + lane];       \
    b##B##h1 = bpv[(cc)*256 + 64 + lane];  \
    b##B##l0 = bpv[(cc)*256 + 128 + lane]; \
    b##B##l1 = bpv[(cc)*256 + 192 + lane]; \
  }

// 3 products (hh, hl, lh); 2 chains per row-tile: u = hh (depth 2), v = hl+lh (depth 4)
#define COMPUTE(B, cc)                                                             \
  {                                                                                \
    float cnv = cns[(cc)*16 + col];                                                \
    f32x4 uA = {0.f, 0.f, 0.f, 0.f};                                               \
    f32x4 uB = {0.f, 0.f, 0.f, 0.f};                                               \
    f32x4 vA = {0.f, 0.f, 0.f, 0.f};                                               \
    f32x4 vB = {0.f, 0.f, 0.f, 0.f};                                               \
    uA = __builtin_amdgcn_mfma_f32_16x16x32_bf16(ah[0][0], b##B##h0, uA, 0, 0, 0); \
    uB = __builtin_amdgcn_mfma_f32_16x16x32_bf16(ah[1][0], b##B##h0, uB, 0, 0, 0); \
    vA = __builtin_amdgcn_mfma_f32_16x16x32_bf16(ah[0][0], b##B##l0, vA, 0, 0, 0); \
    vB = __builtin_amdgcn_mfma_f32_16x16x32_bf16(ah[1][0], b##B##l0, vB, 0, 0, 0); \
    uA = __builtin_amdgcn_mfma_f32_16x16x32_bf16(ah[0][1], b##B##h1, uA, 0, 0, 0); \
    uB = __builtin_amdgcn_mfma_f32_16x16x32_bf16(ah[1][1], b##B##h1, uB, 0, 0, 0); \
    vA = __builtin_amdgcn_mfma_f32_16x16x32_bf16(ah[0][1], b##B##l1, vA, 0, 0, 0); \
    vB = __builtin_amdgcn_mfma_f32_16x16x32_bf16(ah[1][1], b##B##l1, vB, 0, 0, 0); \
    vA = __builtin_amdgcn_mfma_f32_16x16x32_bf16(al[0][0], b##B##h0, vA, 0, 0, 0); \
    vB = __builtin_amdgcn_mfma_f32_16x16x32_bf16(al[1][0], b##B##h0, vB, 0, 0, 0); \
    vA = __builtin_amdgcn_mfma_f32_16x16x32_bf16(al[0][1], b##B##h1, vA, 0, 0, 0); \
    vB = __builtin_amdgcn_mfma_f32_16x16x32_bf16(al[1][1], b##B##h1, vB, 0, 0, 0); \
    const int code = (cc)*16 + col;                                                \
    _Pragma("unroll") for (int r = 0; r < 4; ++r) {                                \
      float v = fmaf(2.f, uA[r] + vA[r], -cnv);                                    \
      v2[0][r] = __builtin_amdgcn_fmed3f(v, v1[0][r], v2[0][r]);                   \
      bool gt = v > v1[0][r];                                                      \
      i1[0][r] = gt ? code : i1[0][r];                                             \
      v1[0][r] = fmaxf(v1[0][r], v);                                               \
    }                                                                              \
    _Pragma("unroll") for (int r = 0; r < 4; ++r) {                                \
      float v = fmaf(2.f, uB[r] + vB[r], -cnv);                                    \
      v2[1][r] = __builtin_amdgcn_fmed3f(v, v1[1][r], v2[1][r]);                   \
      bool gt = v > v1[1][r];                                                      \
      i1[1][r] = gt ? code : i1[1][r];                                             \
      v1[1][r] = fmaxf(v1[1][r], v);                                               \
    }                                                                              \
  }

  LOADB(0, 0);
  LOADB(1, 1);
  LOADB(2, 2);
#pragma unroll 1
  for (int c = 0; c < 63; c += 3) {
    COMPUTE(0, c);
    if (c + 3 < 64) LOADB(0, c + 3);
    COMPUTE(1, c + 1);
    if (c + 4 < 64) LOADB(1, c + 4);
    COMPUTE(2, c + 2);
    if (c + 5 < 64) LOADB(2, c + 5);
  }
  COMPUTE(0, 63);
#undef LOADB
#undef COMPUTE

  // merge top-2 across the 16 col-lanes; butterfly leaves merged result in ALL lanes
#pragma unroll
  for (int rt = 0; rt < 2; ++rt)
#pragma unroll
    for (int r = 0; r < 4; ++r) {
      float bv1 = v1[rt][r], bv2 = v2[rt][r];
      int bidx = i1[rt][r];
#pragma unroll
      for (int off = 1; off <= 8; off <<= 1) {
        float ov1 = __shfl_xor(bv1, off);
        int oi = __shfl_xor(bidx, off);
        float ov2 = __shfl_xor(bv2, off);
        bool take = (ov1 > bv1) || (ov1 == bv1 && oi < bidx);
        float nv2 = take ? fmaxf(bv1, ov2) : fmaxf(bv2, ov1);
        bv1 = take ? ov1 : bv1;
        bidx = take ? oi : bidx;
        bv2 = nv2;
      }
      v1[rt][r] = bv1;
      v2[rt][r] = bv2;
      i1[rt][r] = bidx;
    }

  // in-block exact f64 fixup of ambiguous rows (wave-uniform ballot loop)
#pragma unroll
  for (int rt = 0; rt < 2; ++rt)
#pragma unroll
    for (int r = 0; r < 4; ++r) {
      unsigned long long m = __ballot(col == 0 && (v1[rt][r] - v2[rt][r] < MARGIN));
      while (m) {
        int p = __ffsll((unsigned long long)m) - 1;
        m &= m - 1;
        const int gg = p >> 4;
        const long row = rowbase + rt * 16 + gg * 4 + r;
        __syncthreads();  // done with previous cns use
        cns[lane] = input[(size_t)row * 64 + lane];
        __syncthreads();
        double bt = -1e300;
        int bj = 0;
#pragma unroll 1
        for (int jj = 0; jj < 16; ++jj) {
          const int j = lane * 16 + jj;
          double dot = 0.0, nr = 0.0;
#pragma unroll 4
          for (int d = 0; d < 64; d += 4) {
            float4 evv = *reinterpret_cast<const float4*>(&et[(size_t)j * 64 + d]);
            float4 xv = *reinterpret_cast<const float4*>(&cns[d]);
            dot = fma((double)xv.x, (double)evv.x, dot);
            nr = fma((double)evv.x, (double)evv.x, nr);
            dot = fma((double)xv.y, (double)evv.y, dot);
            nr = fma((double)evv.y, (double)evv.y, nr);
            dot = fma((double)xv.z, (double)evv.z, dot);
            nr = fma((double)evv.z, (double)evv.z, nr);
            dot = fma((double)xv.w, (double)evv.w, dot);
            nr = fma((double)evv.w, (double)evv.w, nr);
          }
          double t = 2.0 * dot - nr;
          if (t > bt) {  // ascending j scan: strict > keeps first max
            bt = t;
            bj = j;
          }
        }
#pragma unroll
        for (int off = 1; off <= 32; off <<= 1) {
          double ot = __shfl_xor(bt, off);
          int oj = __shfl_xor(bj, off);
          if (ot > bt || (ot == bt && oj < bj)) {
            bt = ot;
            bj = oj;
          }
        }
        if (g == gg) i1[rt][r] = bj;  // correct the row's code for its lane group
      }
    }

  // gather hard codes; write out0 + idx; loss
  double lsum = 0.0;
#pragma unroll
  for (int rt = 0; rt < 2; ++rt)
#pragma unroll
    for (int r = 0; r < 4; ++r) {
      const int bidx = i1[rt][r];
      const long row = rowbase + rt * 16 + g * 4 + r;
      float4 h = *reinterpret_cast<const float4*>(&et[(size_t)bidx * 64 + col * 4]);
      float4 x = *reinterpret_cast<const float4*>(&input[(size_t)row * 64 + col * 4]);
      *reinterpret_cast<float4*>(&out[(size_t)row * 64 + col * 4]) = h;
      float d0 = h.x - x.x, d1 = h.y - x.y, d2 = h.z - x.z, d3 = h.w - x.w;
      lsum += (double)(d0 * d0 + d1 * d1 + d2 * d2 + d3 * d3);
      if (col == 0) out[NELEM + row] = (float)bidx;
    }
#pragma unroll
  for (int off = 1; off <= 32; off <<= 1) lsum += __shfl_xor(lsum, off);
  if (lane == 0) unsafeAtomicAdd(&acc[((int)blockIdx.x & 7) * 16], lsum);

  // finalize: last block writes the two scalars
  __threadfence();
  if (lane == 0) {
    int prev = atomicAdd(done, 1);
    if (prev == (int)gridDim.x - 1) {
      __threadfence();
      double v = 0.0;
#pragma unroll
      for (int w = 0; w < 8; ++w) v += unsafeAtomicAdd(&acc[w * 16], 0.0);
      float f = (float)(v / (double)NELEM);
      out[NELEM + NROW + 0] = f;  // diff
      out[NELEM + NROW + 1] = f;  // embed_loss (== diff to ~1e-7 rel)
    }
  }
}

extern "C" void kernel_launch(void* const* d_in, const int* in_sizes, int n_in,
                              void* d_out, int out_size, void* d_ws, size_t ws_size,
                              hipStream_t stream) {
  const float* input = (const float*)d_in[0];
  const float* embed = (const float*)d_in[1];
  float* out = (float*)d_out;
  char* ws = (char*)d_ws;
  ushort_t* bp = (ushort_t*)(ws + OFF_BPACK);
  float* cn = (float*)(ws + OFF_CN);
  float* et = (float*)(ws + OFF_ET);
  double* acc = (double*)(ws + OFF_ACC);
  int* done = (int*)(ws + OFF_DONE);

  prepack_kernel<<<256, 64, 0, stream>>>(embed, bp, cn, et, acc, done);
  score_kernel<<<NBLK, 64, 0, stream>>>(input, bp, cn, et, out, acc, done);
}